// Round 7
// baseline (430.720 us; speedup 1.0000x reference)
//
#include <hip/hip_runtime.h>
#include <hip/hip_bf16.h>

#define B_ 16
#define T_ 32
#define D_ 4096
#define H_ 32
#define HD_ 128
#define MAXS_ 2048
#define M_ (B_*T_)   // 512 rows

typedef __hip_bfloat16 bf16;
typedef __attribute__((ext_vector_type(8))) short bf16x8;
typedef __attribute__((ext_vector_type(4))) float f32x4;

static __device__ __forceinline__ short f2b(float f) {
    bf16 h = __float2bfloat16(f);
    return *reinterpret_cast<short*>(&h);
}
static __device__ __forceinline__ float b2f(short s) {
    bf16 h;
    *reinterpret_cast<short*>(&h) = s;
    return __bfloat162float(h);
}

// async global->LDS, 16B per lane; LDS dest is wave-uniform base + lane*16
#define GLD16(gsrc, ldst) \
    __builtin_amdgcn_global_load_lds((const __attribute__((address_space(1))) void*)(gsrc), \
        (__attribute__((address_space(3))) void*)(ldst), 16, 0, 0)

// ---------------- x f32 -> bf16 ----------------
__global__ __launch_bounds__(256) void conv_x(const float* __restrict__ x, bf16* __restrict__ xb) {
    int idx = blockIdx.x * 256 + threadIdx.x;   // 8-element unit
    const float4* xf = (const float4*)x;
    float4 a = xf[idx * 2], b = xf[idx * 2 + 1];
    bf16x8 o;
    o[0] = f2b(a.x); o[1] = f2b(a.y); o[2] = f2b(a.z); o[3] = f2b(a.w);
    o[4] = f2b(b.x); o[5] = f2b(b.y); o[6] = f2b(b.z); o[7] = f2b(b.w);
    *(bf16x8*)&xb[(size_t)idx * 8] = o;
}

// ---------------- W [k][n] f32 -> Wt [n][k] bf16, 64x64 LDS tiles ----------------
__global__ __launch_bounds__(256) void transpose_w(const float* __restrict__ wq,
        const float* __restrict__ wk, const float* __restrict__ wv,
        const float* __restrict__ wo, bf16* __restrict__ wt) {
    __shared__ float Ts[64][65];   // +1 pad: banks rotate per row
    const int bz = blockIdx.z;
    const float* W = (bz == 0) ? wq : (bz == 1) ? wk : (bz == 2) ? wv : wo;
    const int n0 = blockIdx.x * 64, k0 = blockIdx.y * 64;
    const int t = threadIdx.x;
    {
        int kk = t >> 4, nn = (t & 15) * 4;
        #pragma unroll
        for (int r = 0; r < 4; ++r) {
            float4 v = *(const float4*)&W[(size_t)(k0 + kk + 16 * r) * D_ + n0 + nn];
            Ts[kk + 16 * r][nn + 0] = v.x;
            Ts[kk + 16 * r][nn + 1] = v.y;
            Ts[kk + 16 * r][nn + 2] = v.z;
            Ts[kk + 16 * r][nn + 3] = v.w;
        }
    }
    __syncthreads();
    bf16* dst = wt + (size_t)bz * D_ * D_;   // row block bz*4096
    const int kg = t & 7, nr = t >> 3;
    #pragma unroll
    for (int r = 0; r < 2; ++r) {
        int n = nr + 32 * r;
        bf16x8 o;
        #pragma unroll
        for (int j = 0; j < 8; ++j) o[j] = f2b(Ts[kg * 8 + j][n]);
        *(bf16x8*)&dst[(size_t)(n0 + n) * D_ + k0 + kg * 8] = o;
    }
}

// ---------------- bf16 GEMM, 2-phase double-buffered: prefetch STAGE -> compute -> 1 barrier ----------------
template<int BM, int MODE>
__global__ __launch_bounds__(256) void gemm_bf16t(const bf16* __restrict__ A,
        const bf16* __restrict__ Bt, void* __restrict__ Cout) {
    constexpr int IM = BM / 32;          // A-frags per wave (wave tile BM/2 x 64)
    constexpr int nA = (BM * 64) / 4096; // gload_lds instrs for A tile
    const int K = D_;
    __shared__ bf16 As[2][BM * 32];
    __shared__ bf16 Bs[2][128 * 32];
    const int tid = threadIdx.x, lane = tid & 63, wave = tid >> 6;
    const int wr = wave >> 1, wc = wave & 1;
    const int lg = lane >> 4, li = lane & 15;
    const int row0 = blockIdx.y * BM, col0 = blockIdx.x * 128;
    f32x4 acc[IM][4];
    #pragma unroll
    for (int i = 0; i < IM; ++i)
        #pragma unroll
        for (int j = 0; j < 4; ++j)
            #pragma unroll
            for (int r = 0; r < 4; ++r) acc[i][j][r] = 0.f;

    // stage tile t into buffer buf: linear LDS dest, inverse-swizzled global source
    auto STAGE = [&](int buf, int k0) {
        #pragma unroll
        for (int i = 0; i < nA; ++i) {
            int X = (i * 256 + tid) * 16;              // linear LDS byte
            int row = X >> 6;
            int kb = (X & 63) ^ ((row & 3) << 4);      // inverse swizzle on source
            GLD16(A + (size_t)(row0 + row) * K + k0 + (kb >> 1),
                  (char*)As[buf] + (i * 256 + wave * 64) * 16);
        }
        #pragma unroll
        for (int i = 0; i < 2; ++i) {
            int X = (i * 256 + tid) * 16;
            int row = X >> 6;
            int kb = (X & 63) ^ ((row & 3) << 4);
            GLD16(Bt + (size_t)(col0 + row) * K + k0 + (kb >> 1),
                  (char*)Bs[buf] + (i * 256 + wave * 64) * 16);
        }
    };

    STAGE(0, 0);
    __syncthreads();                     // prologue tile resident (vmcnt(0) folded in)

    const int sw = (li & 3) << 4;
    const int NT = K / 32;
    int cur = 0;
    for (int t = 0; t < NT; ++t) {
        if (t + 1 < NT) STAGE(cur ^ 1, (t + 1) * 32);   // issue next tile, stays in flight over compute
        bf16x8 af[IM], bfr[4];
        #pragma unroll
        for (int i = 0; i < IM; ++i) {
            int row = wr * (BM / 2) + i * 16 + li;
            af[i] = *(const bf16x8*)((const char*)As[cur] + row * 64 + ((lg * 16) ^ sw));
        }
        #pragma unroll
        for (int j = 0; j < 4; ++j) {
            int row = wc * 64 + j * 16 + li;
            bfr[j] = *(const bf16x8*)((const char*)Bs[cur] + row * 64 + ((lg * 16) ^ sw));
        }
        #pragma unroll
        for (int i = 0; i < IM; ++i)
            #pragma unroll
            for (int j = 0; j < 4; ++j)
                acc[i][j] = __builtin_amdgcn_mfma_f32_16x16x32_bf16(af[i], bfr[j], acc[i][j], 0, 0, 0);
        __syncthreads();                 // drains next-tile loads + guards buffer swap (WAR)
        cur ^= 1;
    }
    if (MODE == 0) {
        bf16* Ob = (bf16*)Cout + (size_t)(col0 >> 12) * M_ * D_;
        const int lcol0 = col0 & (D_ - 1);
        #pragma unroll
        for (int i = 0; i < IM; ++i)
            for (int j = 0; j < 4; ++j)
                for (int r = 0; r < 4; ++r) {
                    int row = row0 + wr * (BM / 2) + i * 16 + lg * 4 + r;
                    int col = lcol0 + wc * 64 + j * 16 + li;
                    Ob[(size_t)row * D_ + col] = __float2bfloat16(acc[i][j][r]);
                }
    } else {
        float* O = (float*)Cout;
        #pragma unroll
        for (int i = 0; i < IM; ++i)
            for (int j = 0; j < 4; ++j)
                for (int r = 0; r < 4; ++r) {
                    int row = row0 + wr * (BM / 2) + i * 16 + lg * 4 + r;
                    int col = col0 + wc * 64 + j * 16 + li;
                    O[(size_t)row * D_ + col] = acc[i][j][r];
                }
    }
}

// ---------------- RoPE in-place on bf16 q,k ----------------
__global__ __launch_bounds__(256) void rope_inplace(bf16* __restrict__ qb, bf16* __restrict__ kb) {
    int idx = blockIdx.x * 256 + threadIdx.x;   // 8-element (4-pair) unit
    size_t e0 = (size_t)idx * 8;
    int hd0 = (int)(e0 & 127);
    int t = (int)((e0 >> 12) & 31);
    bf16x8 q = *(bf16x8*)&qb[e0];
    bf16x8 k = *(bf16x8*)&kb[e0];
    bf16x8 qo, ko;
    #pragma unroll
    for (int p = 0; p < 4; ++p) {
        int i = (hd0 >> 1) + p;
        float theta = exp2f(-(float)i * 0.41524101186092787f);  // log2(10000)/32
        float s, c;
        sincosf((float)t * theta, &s, &c);
        float q0 = b2f(q[2 * p]), q1 = b2f(q[2 * p + 1]);
        qo[2 * p]     = f2b(q0 * c - q1 * s);
        qo[2 * p + 1] = f2b(q1 * c + q0 * s);
        float k0 = b2f(k[2 * p]), k1 = b2f(k[2 * p + 1]);
        ko[2 * p]     = f2b(k0 * c - k1 * s);
        ko[2 * p + 1] = f2b(k1 * c + k0 * s);
    }
    *(bf16x8*)&qb[e0] = qo;
    *(bf16x8*)&kb[e0] = ko;
}

// ---------------- Fused flash attention, swapped-QK^T softmax, LDS union ----------------
__global__ __launch_bounds__(256, 3) void attn(const bf16* __restrict__ qb,
        const bf16* __restrict__ kb, const bf16* __restrict__ vb,
        const float* __restrict__ kc, const float* __restrict__ vc,
        const int* __restrict__ spp, bf16* __restrict__ ob) {
    const int bh = blockIdx.x;
    const int b = bh >> 5, h = bh & 31;
    const int sp = *spp;
    const int L = sp + T_;
    const int tid = threadIdx.x, lane = tid & 63, wave = tid >> 6;
    const int lg = lane >> 4, li = lane & 15;

    __shared__ __align__(16) char smem[48256];
    auto Vt   = (short(*)[128][36])smem;               // [4][128][36]
    auto Plds = (bf16(*)[32][40])(smem + 36864);       // [4][32][40]
    auto msh  = (float(*)[32])(smem + 47104);          // [4][32]
    auto lsh  = (float(*)[32])(smem + 47616);          // [4][32]
    float* ltot = (float*)(smem + 48128);              // [32]
    float(*Osh)[128] = (float(*)[128])smem;            // [32][128] (post-loop)

    bf16x8 qf[2][4];
    #pragma unroll
    for (int rt = 0; rt < 2; ++rt)
        #pragma unroll
        for (int kk = 0; kk < 4; ++kk)
            qf[rt][kk] = *(const bf16x8*)(&qb[((size_t)(b * T_ + rt * 16 + li) * H_ + h) * HD_ + kk * 32 + lg * 8]);

    f32x4 o[2][8];
    float m_r[2], l_r[2];
    m_r[0] = m_r[1] = -1e30f;
    l_r[0] = l_r[1] = 0.f;
    #pragma unroll
    for (int rt = 0; rt < 2; ++rt) for (int ht = 0; ht < 8; ++ht) for (int r = 0; r < 4; ++r) o[rt][ht][r] = 0.f;

    const float scale = 0.08838834764831845f;  // 1/sqrt(128)
    const int nch = (L + 31) >> 5;
    for (int c = wave; c < nch; c += 4) {
        const int s0 = c * 32;

        // ---- stage V chunk (32 s x 128 hd) transposed into Vt[wave] ----
        #pragma unroll
        for (int rep = 0; rep < 2; ++rep) {
            int blk = rep * 64 + lane;
            int a = blk >> 5;            // 0..3 : s octet
            int bq = blk & 31;           // hd quad
            short tv[8][4];
            #pragma unroll
            for (int i = 0; i < 8; ++i) {
                int s = s0 + a * 8 + i;
                if (s < sp) {
                    float4 v = *(const float4*)&vc[(((size_t)b * MAXS_ + s) * H_ + h) * HD_ + bq * 4];
                    tv[i][0] = f2b(v.x); tv[i][1] = f2b(v.y); tv[i][2] = f2b(v.z); tv[i][3] = f2b(v.w);
                } else if (s < L) {
                    ushort4 u = *(const ushort4*)&vb[(((size_t)b * T_ + (s - sp)) * H_ + h) * HD_ + bq * 4];
                    tv[i][0] = (short)u.x; tv[i][1] = (short)u.y; tv[i][2] = (short)u.z; tv[i][3] = (short)u.w;
                } else {
                    tv[i][0] = 0; tv[i][1] = 0; tv[i][2] = 0; tv[i][3] = 0;
                }
            }
            #pragma unroll
            for (int j = 0; j < 4; ++j) {
                int row = bq * 4 + j;
                bf16x8 w;
                #pragma unroll
                for (int i = 0; i < 8; ++i) w[i] = tv[i][j];
                int colB = (a * 16) ^ (((row >> 4) & 3) << 4);
                *(bf16x8*)((char*)&Vt[wave][row][0] + colB) = w;
            }
        }

        // ---- K fragments straight from source ----
        bf16x8 kf[2][4];
        #pragma unroll
        for (int ct = 0; ct < 2; ++ct) {
            int s = s0 + ct * 16 + li;
            if (s < sp) {
                const float* kp = &kc[(((size_t)b * MAXS_ + s) * H_ + h) * HD_];
                #pragma unroll
                for (int kk = 0; kk < 4; ++kk) {
                    float4 v0 = *(const float4*)(&kp[kk * 32 + lg * 8]);
                    float4 v1 = *(const float4*)(&kp[kk * 32 + lg * 8 + 4]);
                    bf16x8 f;
                    f[0] = f2b(v0.x); f[1] = f2b(v0.y); f[2] = f2b(v0.z); f[3] = f2b(v0.w);
                    f[4] = f2b(v1.x); f[5] = f2b(v1.y); f[6] = f2b(v1.z); f[7] = f2b(v1.w);
                    kf[ct][kk] = f;
                }
            } else if (s < L) {
                const bf16* kp = &kb[((size_t)(b * T_ + s - sp) * H_ + h) * HD_];
                #pragma unroll
                for (int kk = 0; kk < 4; ++kk)
                    kf[ct][kk] = *(const bf16x8*)(kp + kk * 32 + lg * 8);
            } else {
                #pragma unroll
                for (int kk = 0; kk < 4; ++kk) {
                    bf16x8 f;
                    #pragma unroll
                    for (int j = 0; j < 8; ++j) f[j] = 0;
                    kf[ct][kk] = f;
                }
            }
        }

        // ---- swapped QK^T: sc[ct][rt] = K_slice x Q^T -> D[s16][q16] ----
        f32x4 sc[2][2];
        #pragma unroll
        for (int ct = 0; ct < 2; ++ct)
            #pragma unroll
            for (int rt = 0; rt < 2; ++rt) {
                f32x4 a;
                for (int r = 0; r < 4; ++r) a[r] = 0.f;
                #pragma unroll
                for (int kk = 0; kk < 4; ++kk)
                    a = __builtin_amdgcn_mfma_f32_16x16x32_bf16(kf[ct][kk], qf[rt][kk], a, 0, 0, 0);
                sc[ct][rt] = a;
            }

        // ---- online softmax (per lane: one q-row per rt; s-local = ct*16 + 4*lg + r) ----
        float corr[2];
        #pragma unroll
        for (int rt = 0; rt < 2; ++rt) {
            float xv[8];
            #pragma unroll
            for (int ct = 0; ct < 2; ++ct)
                #pragma unroll
                for (int r = 0; r < 4; ++r) {
                    float xx = sc[ct][rt][r] * scale;
                    if (s0 + ct * 16 + 4 * lg + r >= L) xx = -1e30f;
                    xv[ct * 4 + r] = xx;
                }
            float mx = fmaxf(fmaxf(fmaxf(xv[0], xv[1]), fmaxf(xv[2], xv[3])),
                             fmaxf(fmaxf(xv[4], xv[5]), fmaxf(xv[6], xv[7])));
            mx = fmaxf(mx, __shfl_xor(mx, 16, 64));
            mx = fmaxf(mx, __shfl_xor(mx, 32, 64));
            float mnew = fmaxf(m_r[rt], mx);
            corr[rt] = __expf(m_r[rt] - mnew);
            float p[8], ssum = 0.f;
            #pragma unroll
            for (int j = 0; j < 8; ++j) { p[j] = __expf(xv[j] - mnew); ssum += p[j]; }
            ssum += __shfl_xor(ssum, 16, 64);
            ssum += __shfl_xor(ssum, 32, 64);
            l_r[rt] = l_r[rt] * corr[rt] + ssum;
            m_r[rt] = mnew;
            #pragma unroll
            for (int ct = 0; ct < 2; ++ct)
                #pragma unroll
                for (int r = 0; r < 4; ++r)
                    Plds[wave][rt * 16 + li][ct * 16 + 4 * lg + r] = __float2bfloat16(p[ct * 4 + r]);
        }

        // redistribute corr from q=li indexing to q=4*lg+r indexing, rescale o
        #pragma unroll
        for (int rt = 0; rt < 2; ++rt) {
            float cq[4];
            #pragma unroll
            for (int r = 0; r < 4; ++r) cq[r] = __shfl(corr[rt], 20 * lg + r, 64);
            #pragma unroll
            for (int ht = 0; ht < 8; ++ht)
                #pragma unroll
                for (int r = 0; r < 4; ++r) o[rt][ht][r] *= cq[r];
        }

        // drain wave-private LDS writes (Vt + Plds) before cross-lane reads
        asm volatile("s_waitcnt lgkmcnt(0)" ::: "memory");
        bf16x8 pf[2];
        pf[0] = *(const bf16x8*)(&Plds[wave][li][lg * 8]);
        pf[1] = *(const bf16x8*)(&Plds[wave][16 + li][lg * 8]);

        // ---- PV from transposed LDS ----
        #pragma unroll
        for (int ht = 0; ht < 8; ++ht) {
            int row = ht * 16 + li;
            int colB = (lg * 16) ^ ((ht & 3) << 4);
            bf16x8 vf = *(const bf16x8*)((const char*)&Vt[wave][row][0] + colB);
            #pragma unroll
            for (int rt = 0; rt < 2; ++rt)
                o[rt][ht] = __builtin_amdgcn_mfma_f32_16x16x32_bf16(pf[rt], vf, o[rt][ht], 0, 0, 0);
        }
    }

    // ---- cross-wave combine (m_r/l_r are q=li indexed: one writer lane per row) ----
    if (lg == 0) {
        #pragma unroll
        for (int rt = 0; rt < 2; ++rt) {
            msh[wave][rt * 16 + li] = m_r[rt];
            lsh[wave][rt * 16 + li] = l_r[rt];
        }
    }
    __syncthreads();
    float corr2[2][4];
    #pragma unroll
    for (int rt = 0; rt < 2; ++rt)
        for (int r = 0; r < 4; ++r) {
            int row = rt * 16 + lg * 4 + r;
            float M = fmaxf(fmaxf(msh[0][row], msh[1][row]), fmaxf(msh[2][row], msh[3][row]));
            corr2[rt][r] = __expf(msh[wave][row] - M);
        }
    if (tid < 32) {
        int row = tid;
        float M = fmaxf(fmaxf(msh[0][row], msh[1][row]), fmaxf(msh[2][row], msh[3][row]));
        float lt = 0.f;
        #pragma unroll
        for (int w = 0; w < 4; ++w) lt += lsh[w][row] * __expf(msh[w][row] - M);
        ltot[row] = lt;
    }
    __syncthreads();   // all waves done with msh reads AND Vt (Osh overlays Vt next)
    for (int w = 0; w < 4; ++w) {
        if (wave == w) {
            #pragma unroll
            for (int rt = 0; rt < 2; ++rt)
                for (int ht = 0; ht < 8; ++ht)
                    for (int r = 0; r < 4; ++r) {
                        int row = rt * 16 + lg * 4 + r, col = ht * 16 + li;
                        float val = o[rt][ht][r] * corr2[rt][r];
                        if (w == 0) Osh[row][col] = val;
                        else Osh[row][col] += val;
                    }
        }
        __syncthreads();
    }
    {
        int row = tid >> 3;
        int c0 = (tid & 7) * 16;
        float inv = 1.0f / ltot[row];
        #pragma unroll
        for (int j = 0; j < 16; ++j)
            ob[(size_t)(b * T_ + row) * D_ + h * HD_ + c0 + j] = __float2bfloat16(Osh[row][c0 + j] * inv);
    }
}

extern "C" void kernel_launch(void* const* d_in, const int* in_sizes, int n_in,
                              void* d_out, int out_size, void* d_ws, size_t ws_size,
                              hipStream_t stream) {
    const float* x  = (const float*)d_in[0];
    const float* wq = (const float*)d_in[1];
    const float* wk = (const float*)d_in[2];
    const float* wv = (const float*)d_in[3];
    const float* wo = (const float*)d_in[4];
    const float* kc = (const float*)d_in[5];
    const float* vc = (const float*)d_in[6];
    const int*   sp = (const int*)d_in[7];

    char* ws = (char*)d_ws;
    const size_t MT = (size_t)M_ * D_;                 // 2M elements
    bf16* wt = (bf16*)ws;                              // 128 MiB (wq,wk,wv,wo transposed)
    bf16* xb = wt + (size_t)4 * D_ * D_;
    bf16* qb = xb + MT;
    bf16* kb = qb + MT;
    bf16* vb = kb + MT;
    bf16* ab = vb + MT;

    conv_x<<<dim3((int)(MT / 8 / 256)), 256, 0, stream>>>(x, xb);
    transpose_w<<<dim3(64, 64, 4), 256, 0, stream>>>(wq, wk, wv, wo, wt);
    gemm_bf16t<128, 0><<<dim3(96, 4), 256, 0, stream>>>(xb, wt, qb);
    rope_inplace<<<dim3((int)(MT / 8 / 256)), 256, 0, stream>>>(qb, kb);
    attn<<<dim3(B_ * H_), 256, 0, stream>>>(qb, kb, vb, kc, vc, sp, ab);
    gemm_bf16t<64, 1><<<dim3(32, 8), 256, 0, stream>>>(ab, wt + (size_t)3 * D_ * D_, (float*)d_out);
}

// Round 8
// 398.638 us; speedup vs baseline: 1.0805x; 1.0805x over previous
//
#include <hip/hip_runtime.h>
#include <hip/hip_bf16.h>

#define B_ 16
#define T_ 32
#define D_ 4096
#define H_ 32
#define HD_ 128
#define MAXS_ 2048
#define M_ (B_*T_)   // 512 rows

typedef __hip_bfloat16 bf16;
typedef __attribute__((ext_vector_type(8))) short bf16x8;
typedef __attribute__((ext_vector_type(4))) float f32x4;

static __device__ __forceinline__ short f2b(float f) {
    bf16 h = __float2bfloat16(f);
    return *reinterpret_cast<short*>(&h);
}
static __device__ __forceinline__ float b2f(short s) {
    bf16 h;
    *reinterpret_cast<short*>(&h) = s;
    return __bfloat162float(h);
}

// async global->LDS, 16B per lane; LDS dest is wave-uniform base + lane*16
#define GLD16(gsrc, ldst) \
    __builtin_amdgcn_global_load_lds((const __attribute__((address_space(1))) void*)(gsrc), \
        (__attribute__((address_space(3))) void*)(ldst), 16, 0, 0)

// ---------------- x f32 -> bf16 ----------------
__global__ __launch_bounds__(256) void conv_x(const float* __restrict__ x, bf16* __restrict__ xb) {
    int idx = blockIdx.x * 256 + threadIdx.x;   // 8-element unit
    const float4* xf = (const float4*)x;
    float4 a = xf[idx * 2], b = xf[idx * 2 + 1];
    bf16x8 o;
    o[0] = f2b(a.x); o[1] = f2b(a.y); o[2] = f2b(a.z); o[3] = f2b(a.w);
    o[4] = f2b(b.x); o[5] = f2b(b.y); o[6] = f2b(b.z); o[7] = f2b(b.w);
    *(bf16x8*)&xb[(size_t)idx * 8] = o;
}

// ---------------- W [k][n] f32 -> Wt [n][k] bf16, 64x64 LDS tiles ----------------
__global__ __launch_bounds__(256) void transpose_w(const float* __restrict__ wq,
        const float* __restrict__ wk, const float* __restrict__ wv,
        const float* __restrict__ wo, bf16* __restrict__ wt) {
    __shared__ float Ts[64][65];   // +1 pad: banks rotate per row
    const int bz = blockIdx.z;
    const float* W = (bz == 0) ? wq : (bz == 1) ? wk : (bz == 2) ? wv : wo;
    const int n0 = blockIdx.x * 64, k0 = blockIdx.y * 64;
    const int t = threadIdx.x;
    {
        int kk = t >> 4, nn = (t & 15) * 4;
        #pragma unroll
        for (int r = 0; r < 4; ++r) {
            float4 v = *(const float4*)&W[(size_t)(k0 + kk + 16 * r) * D_ + n0 + nn];
            Ts[kk + 16 * r][nn + 0] = v.x;
            Ts[kk + 16 * r][nn + 1] = v.y;
            Ts[kk + 16 * r][nn + 2] = v.z;
            Ts[kk + 16 * r][nn + 3] = v.w;
        }
    }
    __syncthreads();
    bf16* dst = wt + (size_t)bz * D_ * D_;   // row block bz*4096
    const int kg = t & 7, nr = t >> 3;
    #pragma unroll
    for (int r = 0; r < 2; ++r) {
        int n = nr + 32 * r;
        bf16x8 o;
        #pragma unroll
        for (int j = 0; j < 8; ++j) o[j] = f2b(Ts[kg * 8 + j][n]);
        *(bf16x8*)&dst[(size_t)(n0 + n) * D_ + k0 + kg * 8] = o;
    }
}

// ---------------- bf16 GEMM, m97 structure (single-buffer), generalized tile ----------------
// A: [M][K] bf16 row-major. Bt: [N][K] bf16. Wave grid 2x2, wave tile (BM/2)x(BN/2).
template<int BM, int BN, int MODE>
__global__ __launch_bounds__(256) void gemm_bf16t(const bf16* __restrict__ A,
        const bf16* __restrict__ Bt, void* __restrict__ Cout) {
    constexpr int IM = BM / 32;          // A-frags per wave
    constexpr int JN = BN / 32;          // B-frags per wave
    constexpr int nA = (BM * 64) / 4096; // gload_lds instrs per thread for A tile
    constexpr int nB = (BN * 64) / 4096;
    const int K = D_;
    __shared__ bf16 As[BM * 32];
    __shared__ bf16 Bs[BN * 32];
    const int tid = threadIdx.x, lane = tid & 63, wave = tid >> 6;
    const int wr = wave >> 1, wc = wave & 1;
    const int lg = lane >> 4, li = lane & 15;
    const int row0 = blockIdx.y * BM, col0 = blockIdx.x * BN;
    f32x4 acc[IM][JN];
    #pragma unroll
    for (int i = 0; i < IM; ++i)
        #pragma unroll
        for (int j = 0; j < JN; ++j)
            #pragma unroll
            for (int r = 0; r < 4; ++r) acc[i][j][r] = 0.f;

    const int sw = (li & 3) << 4;
    for (int k0 = 0; k0 < K; k0 += 32) {
        #pragma unroll
        for (int i = 0; i < nA; ++i) {
            int X = (i * 256 + tid) * 16;              // linear LDS byte
            int row = X >> 6;
            int kb = (X & 63) ^ ((row & 3) << 4);      // inverse swizzle on source
            GLD16(A + (size_t)(row0 + row) * K + k0 + (kb >> 1),
                  (char*)As + (i * 256 + wave * 64) * 16);
        }
        #pragma unroll
        for (int i = 0; i < nB; ++i) {
            int X = (i * 256 + tid) * 16;
            int row = X >> 6;
            int kb = (X & 63) ^ ((row & 3) << 4);
            GLD16(Bt + (size_t)(col0 + row) * K + k0 + (kb >> 1),
                  (char*)Bs + (i * 256 + wave * 64) * 16);
        }
        __syncthreads();
        bf16x8 af[IM], bfr[JN];
        #pragma unroll
        for (int i = 0; i < IM; ++i) {
            int row = wr * (BM / 2) + i * 16 + li;
            af[i] = *(const bf16x8*)((const char*)As + row * 64 + ((lg * 16) ^ sw));
        }
        #pragma unroll
        for (int j = 0; j < JN; ++j) {
            int row = wc * (BN / 2) + j * 16 + li;
            bfr[j] = *(const bf16x8*)((const char*)Bs + row * 64 + ((lg * 16) ^ sw));
        }
        #pragma unroll
        for (int i = 0; i < IM; ++i)
            #pragma unroll
            for (int j = 0; j < JN; ++j)
                acc[i][j] = __builtin_amdgcn_mfma_f32_16x16x32_bf16(af[i], bfr[j], acc[i][j], 0, 0, 0);
        __syncthreads();
    }
    if (MODE == 0) {
        bf16* Ob = (bf16*)Cout + (size_t)(col0 >> 12) * M_ * D_;
        const int lcol0 = col0 & (D_ - 1);
        #pragma unroll
        for (int i = 0; i < IM; ++i)
            for (int j = 0; j < JN; ++j)
                for (int r = 0; r < 4; ++r) {
                    int row = row0 + wr * (BM / 2) + i * 16 + lg * 4 + r;
                    int col = lcol0 + wc * (BN / 2) + j * 16 + li;
                    Ob[(size_t)row * D_ + col] = __float2bfloat16(acc[i][j][r]);
                }
    } else {
        float* O = (float*)Cout;
        #pragma unroll
        for (int i = 0; i < IM; ++i)
            for (int j = 0; j < JN; ++j)
                for (int r = 0; r < 4; ++r) {
                    int row = row0 + wr * (BM / 2) + i * 16 + lg * 4 + r;
                    int col = col0 + wc * (BN / 2) + j * 16 + li;
                    O[(size_t)row * D_ + col] = acc[i][j][r];
                }
    }
}

// ---------------- RoPE in-place on bf16 q,k ----------------
__global__ __launch_bounds__(256) void rope_inplace(bf16* __restrict__ qb, bf16* __restrict__ kb) {
    int idx = blockIdx.x * 256 + threadIdx.x;   // 8-element (4-pair) unit
    size_t e0 = (size_t)idx * 8;
    int hd0 = (int)(e0 & 127);
    int t = (int)((e0 >> 12) & 31);
    bf16x8 q = *(bf16x8*)&qb[e0];
    bf16x8 k = *(bf16x8*)&kb[e0];
    bf16x8 qo, ko;
    #pragma unroll
    for (int p = 0; p < 4; ++p) {
        int i = (hd0 >> 1) + p;
        float theta = exp2f(-(float)i * 0.41524101186092787f);  // log2(10000)/32
        float s, c;
        sincosf((float)t * theta, &s, &c);
        float q0 = b2f(q[2 * p]), q1 = b2f(q[2 * p + 1]);
        qo[2 * p]     = f2b(q0 * c - q1 * s);
        qo[2 * p + 1] = f2b(q1 * c + q0 * s);
        float k0 = b2f(k[2 * p]), k1 = b2f(k[2 * p + 1]);
        ko[2 * p]     = f2b(k0 * c - k1 * s);
        ko[2 * p + 1] = f2b(k1 * c + k0 * s);
    }
    *(bf16x8*)&qb[e0] = qo;
    *(bf16x8*)&kb[e0] = ko;
}

// ---------------- Fused flash attention, swapped-QK^T softmax, LDS union ----------------
__global__ __launch_bounds__(256, 3) void attn(const bf16* __restrict__ qb,
        const bf16* __restrict__ kb, const bf16* __restrict__ vb,
        const float* __restrict__ kc, const float* __restrict__ vc,
        const int* __restrict__ spp, bf16* __restrict__ ob) {
    const int bh = blockIdx.x;
    const int b = bh >> 5, h = bh & 31;
    const int sp = *spp;
    const int L = sp + T_;
    const int tid = threadIdx.x, lane = tid & 63, wave = tid >> 6;
    const int lg = lane >> 4, li = lane & 15;

    __shared__ __align__(16) char smem[48256];
    auto Vt   = (short(*)[128][36])smem;               // [4][128][36]
    auto Plds = (bf16(*)[32][40])(smem + 36864);       // [4][32][40]
    auto msh  = (float(*)[32])(smem + 47104);          // [4][32]
    auto lsh  = (float(*)[32])(smem + 47616);          // [4][32]
    float* ltot = (float*)(smem + 48128);              // [32]
    float(*Osh)[128] = (float(*)[128])smem;            // [32][128] (post-loop)

    bf16x8 qf[2][4];
    #pragma unroll
    for (int rt = 0; rt < 2; ++rt)
        #pragma unroll
        for (int kk = 0; kk < 4; ++kk)
            qf[rt][kk] = *(const bf16x8*)(&qb[((size_t)(b * T_ + rt * 16 + li) * H_ + h) * HD_ + kk * 32 + lg * 8]);

    f32x4 o[2][8];
    float m_r[2], l_r[2];
    m_r[0] = m_r[1] = -1e30f;
    l_r[0] = l_r[1] = 0.f;
    #pragma unroll
    for (int rt = 0; rt < 2; ++rt) for (int ht = 0; ht < 8; ++ht) for (int r = 0; r < 4; ++r) o[rt][ht][r] = 0.f;

    const float scale = 0.08838834764831845f;  // 1/sqrt(128)
    const int nch = (L + 31) >> 5;
    for (int c = wave; c < nch; c += 4) {
        const int s0 = c * 32;

        // ---- stage V chunk (32 s x 128 hd) transposed into Vt[wave] ----
        #pragma unroll
        for (int rep = 0; rep < 2; ++rep) {
            int blk = rep * 64 + lane;
            int a = blk >> 5;            // 0..3 : s octet
            int bq = blk & 31;           // hd quad
            short tv[8][4];
            #pragma unroll
            for (int i = 0; i < 8; ++i) {
                int s = s0 + a * 8 + i;
                if (s < sp) {
                    float4 v = *(const float4*)&vc[(((size_t)b * MAXS_ + s) * H_ + h) * HD_ + bq * 4];
                    tv[i][0] = f2b(v.x); tv[i][1] = f2b(v.y); tv[i][2] = f2b(v.z); tv[i][3] = f2b(v.w);
                } else if (s < L) {
                    ushort4 u = *(const ushort4*)&vb[(((size_t)b * T_ + (s - sp)) * H_ + h) * HD_ + bq * 4];
                    tv[i][0] = (short)u.x; tv[i][1] = (short)u.y; tv[i][2] = (short)u.z; tv[i][3] = (short)u.w;
                } else {
                    tv[i][0] = 0; tv[i][1] = 0; tv[i][2] = 0; tv[i][3] = 0;
                }
            }
            #pragma unroll
            for (int j = 0; j < 4; ++j) {
                int row = bq * 4 + j;
                bf16x8 w;
                #pragma unroll
                for (int i = 0; i < 8; ++i) w[i] = tv[i][j];
                int colB = (a * 16) ^ (((row >> 4) & 3) << 4);
                *(bf16x8*)((char*)&Vt[wave][row][0] + colB) = w;
            }
        }

        // ---- K fragments straight from source ----
        bf16x8 kf[2][4];
        #pragma unroll
        for (int ct = 0; ct < 2; ++ct) {
            int s = s0 + ct * 16 + li;
            if (s < sp) {
                const float* kp = &kc[(((size_t)b * MAXS_ + s) * H_ + h) * HD_];
                #pragma unroll
                for (int kk = 0; kk < 4; ++kk) {
                    float4 v0 = *(const float4*)(&kp[kk * 32 + lg * 8]);
                    float4 v1 = *(const float4*)(&kp[kk * 32 + lg * 8 + 4]);
                    bf16x8 f;
                    f[0] = f2b(v0.x); f[1] = f2b(v0.y); f[2] = f2b(v0.z); f[3] = f2b(v0.w);
                    f[4] = f2b(v1.x); f[5] = f2b(v1.y); f[6] = f2b(v1.z); f[7] = f2b(v1.w);
                    kf[ct][kk] = f;
                }
            } else if (s < L) {
                const bf16* kp = &kb[((size_t)(b * T_ + s - sp) * H_ + h) * HD_];
                #pragma unroll
                for (int kk = 0; kk < 4; ++kk)
                    kf[ct][kk] = *(const bf16x8*)(kp + kk * 32 + lg * 8);
            } else {
                #pragma unroll
                for (int kk = 0; kk < 4; ++kk) {
                    bf16x8 f;
                    #pragma unroll
                    for (int j = 0; j < 8; ++j) f[j] = 0;
                    kf[ct][kk] = f;
                }
            }
        }

        // ---- swapped QK^T: sc[ct][rt] = K_slice x Q^T -> D[s16][q16] ----
        f32x4 sc[2][2];
        #pragma unroll
        for (int ct = 0; ct < 2; ++ct)
            #pragma unroll
            for (int rt = 0; rt < 2; ++rt) {
                f32x4 a;
                for (int r = 0; r < 4; ++r) a[r] = 0.f;
                #pragma unroll
                for (int kk = 0; kk < 4; ++kk)
                    a = __builtin_amdgcn_mfma_f32_16x16x32_bf16(kf[ct][kk], qf[rt][kk], a, 0, 0, 0);
                sc[ct][rt] = a;
            }

        // ---- online softmax (per lane: one q-row per rt; s-local = ct*16 + 4*lg + r) ----
        float corr[2];
        #pragma unroll
        for (int rt = 0; rt < 2; ++rt) {
            float xv[8];
            #pragma unroll
            for (int ct = 0; ct < 2; ++ct)
                #pragma unroll
                for (int r = 0; r < 4; ++r) {
                    float xx = sc[ct][rt][r] * scale;
                    if (s0 + ct * 16 + 4 * lg + r >= L) xx = -1e30f;
                    xv[ct * 4 + r] = xx;
                }
            float mx = fmaxf(fmaxf(fmaxf(xv[0], xv[1]), fmaxf(xv[2], xv[3])),
                             fmaxf(fmaxf(xv[4], xv[5]), fmaxf(xv[6], xv[7])));
            mx = fmaxf(mx, __shfl_xor(mx, 16, 64));
            mx = fmaxf(mx, __shfl_xor(mx, 32, 64));
            float mnew = fmaxf(m_r[rt], mx);
            corr[rt] = __expf(m_r[rt] - mnew);
            float p[8], ssum = 0.f;
            #pragma unroll
            for (int j = 0; j < 8; ++j) { p[j] = __expf(xv[j] - mnew); ssum += p[j]; }
            ssum += __shfl_xor(ssum, 16, 64);
            ssum += __shfl_xor(ssum, 32, 64);
            l_r[rt] = l_r[rt] * corr[rt] + ssum;
            m_r[rt] = mnew;
            #pragma unroll
            for (int ct = 0; ct < 2; ++ct)
                #pragma unroll
                for (int r = 0; r < 4; ++r)
                    Plds[wave][rt * 16 + li][ct * 16 + 4 * lg + r] = __float2bfloat16(p[ct * 4 + r]);
        }

        // redistribute corr from q=li indexing to q=4*lg+r indexing, rescale o
        #pragma unroll
        for (int rt = 0; rt < 2; ++rt) {
            float cq[4];
            #pragma unroll
            for (int r = 0; r < 4; ++r) cq[r] = __shfl(corr[rt], 20 * lg + r, 64);
            #pragma unroll
            for (int ht = 0; ht < 8; ++ht)
                #pragma unroll
                for (int r = 0; r < 4; ++r) o[rt][ht][r] *= cq[r];
        }

        // drain wave-private LDS writes (Vt + Plds) before cross-lane reads
        asm volatile("s_waitcnt lgkmcnt(0)" ::: "memory");
        bf16x8 pf[2];
        pf[0] = *(const bf16x8*)(&Plds[wave][li][lg * 8]);
        pf[1] = *(const bf16x8*)(&Plds[wave][16 + li][lg * 8]);

        // ---- PV from transposed LDS ----
        #pragma unroll
        for (int ht = 0; ht < 8; ++ht) {
            int row = ht * 16 + li;
            int colB = (lg * 16) ^ ((ht & 3) << 4);
            bf16x8 vf = *(const bf16x8*)((const char*)&Vt[wave][row][0] + colB);
            #pragma unroll
            for (int rt = 0; rt < 2; ++rt)
                o[rt][ht] = __builtin_amdgcn_mfma_f32_16x16x32_bf16(pf[rt], vf, o[rt][ht], 0, 0, 0);
        }
    }

    // ---- cross-wave combine (m_r/l_r are q=li indexed: one writer lane per row) ----
    if (lg == 0) {
        #pragma unroll
        for (int rt = 0; rt < 2; ++rt) {
            msh[wave][rt * 16 + li] = m_r[rt];
            lsh[wave][rt * 16 + li] = l_r[rt];
        }
    }
    __syncthreads();
    float corr2[2][4];
    #pragma unroll
    for (int rt = 0; rt < 2; ++rt)
        for (int r = 0; r < 4; ++r) {
            int row = rt * 16 + lg * 4 + r;
            float M = fmaxf(fmaxf(msh[0][row], msh[1][row]), fmaxf(msh[2][row], msh[3][row]));
            corr2[rt][r] = __expf(msh[wave][row] - M);
        }
    if (tid < 32) {
        int row = tid;
        float M = fmaxf(fmaxf(msh[0][row], msh[1][row]), fmaxf(msh[2][row], msh[3][row]));
        float lt = 0.f;
        #pragma unroll
        for (int w = 0; w < 4; ++w) lt += lsh[w][row] * __expf(msh[w][row] - M);
        ltot[row] = lt;
    }
    __syncthreads();   // all waves done with msh reads AND Vt (Osh overlays Vt next)
    for (int w = 0; w < 4; ++w) {
        if (wave == w) {
            #pragma unroll
            for (int rt = 0; rt < 2; ++rt)
                for (int ht = 0; ht < 8; ++ht)
                    for (int r = 0; r < 4; ++r) {
                        int row = rt * 16 + lg * 4 + r, col = ht * 16 + li;
                        float val = o[rt][ht][r] * corr2[rt][r];
                        if (w == 0) Osh[row][col] = val;
                        else Osh[row][col] += val;
                    }
        }
        __syncthreads();
    }
    {
        int row = tid >> 3;
        int c0 = (tid & 7) * 16;
        float inv = 1.0f / ltot[row];
        #pragma unroll
        for (int j = 0; j < 16; ++j)
            ob[(size_t)(b * T_ + row) * D_ + h * HD_ + c0 + j] = __float2bfloat16(Osh[row][c0 + j] * inv);
    }
}

extern "C" void kernel_launch(void* const* d_in, const int* in_sizes, int n_in,
                              void* d_out, int out_size, void* d_ws, size_t ws_size,
                              hipStream_t stream) {
    const float* x  = (const float*)d_in[0];
    const float* wq = (const float*)d_in[1];
    const float* wk = (const float*)d_in[2];
    const float* wv = (const float*)d_in[3];
    const float* wo = (const float*)d_in[4];
    const float* kc = (const float*)d_in[5];
    const float* vc = (const float*)d_in[6];
    const int*   sp = (const int*)d_in[7];

    char* ws = (char*)d_ws;
    const size_t MT = (size_t)M_ * D_;                 // 2M elements
    bf16* wt = (bf16*)ws;                              // 128 MiB (wq,wk,wv,wo transposed)
    bf16* xb = wt + (size_t)4 * D_ * D_;
    bf16* qb = xb + MT;
    bf16* kb = qb + MT;
    bf16* vb = kb + MT;
    bf16* ab = vb + MT;

    conv_x<<<dim3((int)(MT / 8 / 256)), 256, 0, stream>>>(x, xb);
    transpose_w<<<dim3(64, 64, 4), 256, 0, stream>>>(wq, wk, wv, wo, wt);
    // QKV: BM=64 -> 768 blocks (3/CU)
    gemm_bf16t<64, 128, 0><<<dim3(96, 8), 256, 0, stream>>>(xb, wt, qb);
    rope_inplace<<<dim3((int)(MT / 8 / 256)), 256, 0, stream>>>(qb, kb);
    attn<<<dim3(B_ * H_), 256, 0, stream>>>(qb, kb, vb, kc, vc, sp, ab);
    // wo: 64x64 tiles -> 512 blocks (2/CU)
    gemm_bf16t<64, 64, 1><<<dim3(64, 8), 256, 0, stream>>>(ab, wt + (size_t)3 * D_ * D_, (float*)d_out);
}

// Round 9
// 359.718 us; speedup vs baseline: 1.1974x; 1.1082x over previous
//
#include <hip/hip_runtime.h>
#include <hip/hip_bf16.h>

#define B_ 16
#define T_ 32
#define D_ 4096
#define H_ 32
#define HD_ 128
#define MAXS_ 2048
#define M_ (B_*T_)   // 512 rows

typedef __hip_bfloat16 bf16;
typedef __attribute__((ext_vector_type(8))) short bf16x8;
typedef __attribute__((ext_vector_type(4))) float f32x4;

static __device__ __forceinline__ short f2b(float f) {
    bf16 h = __float2bfloat16(f);
    return *reinterpret_cast<short*>(&h);
}
static __device__ __forceinline__ float b2f(short s) {
    bf16 h;
    *reinterpret_cast<short*>(&h) = s;
    return __bfloat162float(h);
}

// async global->LDS, 16B per lane; LDS dest is wave-uniform base + lane*16
#define GLD16(gsrc, ldst) \
    __builtin_amdgcn_global_load_lds((const __attribute__((address_space(1))) void*)(gsrc), \
        (__attribute__((address_space(3))) void*)(ldst), 16, 0, 0)

// ---------------- x f32 -> bf16 ----------------
__global__ __launch_bounds__(256) void conv_x(const float* __restrict__ x, bf16* __restrict__ xb) {
    int idx = blockIdx.x * 256 + threadIdx.x;   // 8-element unit
    const float4* xf = (const float4*)x;
    float4 a = xf[idx * 2], b = xf[idx * 2 + 1];
    bf16x8 o;
    o[0] = f2b(a.x); o[1] = f2b(a.y); o[2] = f2b(a.z); o[3] = f2b(a.w);
    o[4] = f2b(b.x); o[5] = f2b(b.y); o[6] = f2b(b.z); o[7] = f2b(b.w);
    *(bf16x8*)&xb[(size_t)idx * 8] = o;
}

// ---------------- single W [k][n] f32 -> Wt [n][k] bf16 (wo only) ----------------
__global__ __launch_bounds__(256) void transpose_w(const float* __restrict__ W, bf16* __restrict__ wt) {
    __shared__ float Ts[64][65];
    const int n0 = blockIdx.x * 64, k0 = blockIdx.y * 64;
    const int t = threadIdx.x;
    {
        int kk = t >> 4, nn = (t & 15) * 4;
        #pragma unroll
        for (int r = 0; r < 4; ++r) {
            float4 v = *(const float4*)&W[(size_t)(k0 + kk + 16 * r) * D_ + n0 + nn];
            Ts[kk + 16 * r][nn + 0] = v.x;
            Ts[kk + 16 * r][nn + 1] = v.y;
            Ts[kk + 16 * r][nn + 2] = v.z;
            Ts[kk + 16 * r][nn + 3] = v.w;
        }
    }
    __syncthreads();
    const int kg = t & 7, nr = t >> 3;
    #pragma unroll
    for (int r = 0; r < 2; ++r) {
        int n = nr + 32 * r;
        bf16x8 o;
        #pragma unroll
        for (int j = 0; j < 8; ++j) o[j] = f2b(Ts[kg * 8 + j][n]);
        *(bf16x8*)&wt[(size_t)(n0 + n) * D_ + k0 + kg * 8] = o;
    }
}

// ---------------- QKV GEMM with fused weight transpose+convert ----------------
// A: xb bf16 [512][4096] via gload_lds. B: raw f32 W [k][n], reg-transposed to Bs.
// BM=64, BN=128, grid (96, 8): blockIdx.x>>5 selects wq/wk/wv.
__global__ __launch_bounds__(256) void gemm_qkvw(const bf16* __restrict__ A,
        const float* __restrict__ wq, const float* __restrict__ wk,
        const float* __restrict__ wv, bf16* __restrict__ out) {
    const int K = D_;
    const int wsel = blockIdx.x >> 5;
    const float* W = (wsel == 0) ? wq : (wsel == 1) ? wk : wv;
    const int lcol0 = (blockIdx.x & 31) * 128;
    bf16* Ob = out + (size_t)wsel * M_ * D_;
    __shared__ bf16 As[64 * 32];
    __shared__ short Bs[128][40];        // 80B stride: 16B-aligned reads, ~2-way banks
    const int tid = threadIdx.x, lane = tid & 63, wave = tid >> 6;
    const int wr = wave >> 1, wc = wave & 1;
    const int lg = lane >> 4, li = lane & 15;
    const int row0 = blockIdx.y * 64;
    const int bq = tid & 31, kq = tid >> 5;   // B-staging unit: 4k x 4n
    f32x4 acc[2][4];
    #pragma unroll
    for (int i = 0; i < 2; ++i)
        #pragma unroll
        for (int j = 0; j < 4; ++j)
            #pragma unroll
            for (int r = 0; r < 4; ++r) acc[i][j][r] = 0.f;

    const int sw = (li & 3) << 4;
    for (int k0 = 0; k0 < K; k0 += 32) {
        // ---- B: load 4 float4 (coalesced along n), transpose in reg, bf16 ds_write ----
        float4 wv4[4];
        #pragma unroll
        for (int i = 0; i < 4; ++i)
            wv4[i] = *(const float4*)&W[(size_t)(k0 + kq * 4 + i) * D_ + lcol0 + bq * 4];
        // ---- A: 1 gload_lds per thread (64x32 bf16 = 4KB), linear dest + inv-swz source ----
        {
            int X = tid * 16;
            int row = X >> 6;
            int kb = (X & 63) ^ ((row & 3) << 4);
            GLD16(A + (size_t)(row0 + row) * K + k0 + (kb >> 1),
                  (char*)As + wave * 1024);
        }
        #pragma unroll
        for (int j = 0; j < 4; ++j) {
            int n = bq * 4 + j;
            short4 col;
            col.x = f2b(((const float*)&wv4[0])[j]);
            col.y = f2b(((const float*)&wv4[1])[j]);
            col.z = f2b(((const float*)&wv4[2])[j]);
            col.w = f2b(((const float*)&wv4[3])[j]);
            *(short4*)((char*)&Bs[n][0] + ((kq * 8) ^ (((n >> 4) & 3) << 4))) = col;
        }
        __syncthreads();
        bf16x8 af[2], bfr[4];
        #pragma unroll
        for (int i = 0; i < 2; ++i) {
            int row = wr * 32 + i * 16 + li;
            af[i] = *(const bf16x8*)((const char*)As + row * 64 + ((lg * 16) ^ sw));
        }
        #pragma unroll
        for (int j = 0; j < 4; ++j) {
            int row = wc * 64 + j * 16 + li;
            bfr[j] = *(const bf16x8*)((const char*)&Bs[row][0] + ((lg * 16) ^ (((row >> 4) & 3) << 4)));
        }
        #pragma unroll
        for (int i = 0; i < 2; ++i)
            #pragma unroll
            for (int j = 0; j < 4; ++j)
                acc[i][j] = __builtin_amdgcn_mfma_f32_16x16x32_bf16(af[i], bfr[j], acc[i][j], 0, 0, 0);
        __syncthreads();
    }
    #pragma unroll
    for (int i = 0; i < 2; ++i)
        for (int j = 0; j < 4; ++j)
            for (int r = 0; r < 4; ++r) {
                int row = row0 + wr * 32 + i * 16 + lg * 4 + r;
                int col = lcol0 + wc * 64 + j * 16 + li;
                Ob[(size_t)row * D_ + col] = __float2bfloat16(acc[i][j][r]);
            }
}

// ---------------- bf16 GEMM (pre-transposed Bt), m97 structure — used for wo ----------------
template<int BM, int BN>
__global__ __launch_bounds__(256) void gemm_bf16t(const bf16* __restrict__ A,
        const bf16* __restrict__ Bt, float* __restrict__ O) {
    constexpr int IM = BM / 32;
    constexpr int JN = BN / 32;
    constexpr int nA = (BM * 64) / 4096;
    constexpr int nB = (BN * 64) / 4096;
    const int K = D_;
    __shared__ bf16 As[BM * 32];
    __shared__ bf16 Bs[BN * 32];
    const int tid = threadIdx.x, lane = tid & 63, wave = tid >> 6;
    const int wr = wave >> 1, wc = wave & 1;
    const int lg = lane >> 4, li = lane & 15;
    const int row0 = blockIdx.y * BM, col0 = blockIdx.x * BN;
    f32x4 acc[IM][JN];
    #pragma unroll
    for (int i = 0; i < IM; ++i)
        #pragma unroll
        for (int j = 0; j < JN; ++j)
            #pragma unroll
            for (int r = 0; r < 4; ++r) acc[i][j][r] = 0.f;

    const int sw = (li & 3) << 4;
    for (int k0 = 0; k0 < K; k0 += 32) {
        #pragma unroll
        for (int i = 0; i < nA; ++i) {
            int X = (i * 256 + tid) * 16;
            int row = X >> 6;
            int kb = (X & 63) ^ ((row & 3) << 4);
            GLD16(A + (size_t)(row0 + row) * K + k0 + (kb >> 1),
                  (char*)As + (i * 256 + wave * 64) * 16);
        }
        #pragma unroll
        for (int i = 0; i < nB; ++i) {
            int X = (i * 256 + tid) * 16;
            int row = X >> 6;
            int kb = (X & 63) ^ ((row & 3) << 4);
            GLD16(Bt + (size_t)(col0 + row) * K + k0 + (kb >> 1),
                  (char*)Bs + (i * 256 + wave * 64) * 16);
        }
        __syncthreads();
        bf16x8 af[IM], bfr[JN];
        #pragma unroll
        for (int i = 0; i < IM; ++i) {
            int row = wr * (BM / 2) + i * 16 + li;
            af[i] = *(const bf16x8*)((const char*)As + row * 64 + ((lg * 16) ^ sw));
        }
        #pragma unroll
        for (int j = 0; j < JN; ++j) {
            int row = wc * (BN / 2) + j * 16 + li;
            bfr[j] = *(const bf16x8*)((const char*)Bs + row * 64 + ((lg * 16) ^ sw));
        }
        #pragma unroll
        for (int i = 0; i < IM; ++i)
            #pragma unroll
            for (int j = 0; j < JN; ++j)
                acc[i][j] = __builtin_amdgcn_mfma_f32_16x16x32_bf16(af[i], bfr[j], acc[i][j], 0, 0, 0);
        __syncthreads();
    }
    #pragma unroll
    for (int i = 0; i < IM; ++i)
        for (int j = 0; j < JN; ++j)
            for (int r = 0; r < 4; ++r) {
                int row = row0 + wr * (BM / 2) + i * 16 + lg * 4 + r;
                int col = col0 + wc * (BN / 2) + j * 16 + li;
                O[(size_t)row * D_ + col] = acc[i][j][r];
            }
}

// ---------------- RoPE in-place on bf16 q,k ----------------
__global__ __launch_bounds__(256) void rope_inplace(bf16* __restrict__ qb, bf16* __restrict__ kb) {
    int idx = blockIdx.x * 256 + threadIdx.x;
    size_t e0 = (size_t)idx * 8;
    int hd0 = (int)(e0 & 127);
    int t = (int)((e0 >> 12) & 31);
    bf16x8 q = *(bf16x8*)&qb[e0];
    bf16x8 k = *(bf16x8*)&kb[e0];
    bf16x8 qo, ko;
    #pragma unroll
    for (int p = 0; p < 4; ++p) {
        int i = (hd0 >> 1) + p;
        float theta = exp2f(-(float)i * 0.41524101186092787f);  // log2(10000)/32
        float s, c;
        sincosf((float)t * theta, &s, &c);
        float q0 = b2f(q[2 * p]), q1 = b2f(q[2 * p + 1]);
        qo[2 * p]     = f2b(q0 * c - q1 * s);
        qo[2 * p + 1] = f2b(q1 * c + q0 * s);
        float k0 = b2f(k[2 * p]), k1 = b2f(k[2 * p + 1]);
        ko[2 * p]     = f2b(k0 * c - k1 * s);
        ko[2 * p + 1] = f2b(k1 * c + k0 * s);
    }
    *(bf16x8*)&qb[e0] = qo;
    *(bf16x8*)&kb[e0] = ko;
}

// ---------------- Fused flash attention, swapped-QK^T, chunk-uniform source paths ----------------
__global__ __launch_bounds__(256, 3) void attn(const bf16* __restrict__ qb,
        const bf16* __restrict__ kb, const bf16* __restrict__ vb,
        const float* __restrict__ kc, const float* __restrict__ vc,
        const int* __restrict__ spp, bf16* __restrict__ ob) {
    const int bh = blockIdx.x;
    const int b = bh >> 5, h = bh & 31;
    const int sp = *spp;
    const int L = sp + T_;
    const int tid = threadIdx.x, lane = tid & 63, wave = tid >> 6;
    const int lg = lane >> 4, li = lane & 15;

    // Vt: [4][128][40] shorts (80B stride, 16B-aligned b128) | Plds [4][32][40] | m/l/ltot
    __shared__ __align__(16) char smem[52352];
    auto Vt   = (short(*)[128][40])smem;               // 40960 B
    auto Plds = (bf16(*)[32][40])(smem + 40960);       // 10240 B
    auto msh  = (float(*)[32])(smem + 51200);
    auto lsh  = (float(*)[32])(smem + 51712);
    float* ltot = (float*)(smem + 52224);
    float(*Osh)[128] = (float(*)[128])smem;            // post-loop overlay

    bf16x8 qf[2][4];
    #pragma unroll
    for (int rt = 0; rt < 2; ++rt)
        #pragma unroll
        for (int kk = 0; kk < 4; ++kk)
            qf[rt][kk] = *(const bf16x8*)(&qb[((size_t)(b * T_ + rt * 16 + li) * H_ + h) * HD_ + kk * 32 + lg * 8]);

    f32x4 o[2][8];
    float m_r[2], l_r[2];
    m_r[0] = m_r[1] = -1e30f;
    l_r[0] = l_r[1] = 0.f;
    #pragma unroll
    for (int rt = 0; rt < 2; ++rt) for (int ht = 0; ht < 8; ++ht) for (int r = 0; r < 4; ++r) o[rt][ht][r] = 0.f;

    const float scale = 0.08838834764831845f;  // 1/sqrt(128)
    const int nch = (L + 31) >> 5;
    for (int c = wave; c < nch; c += 4) {
        const int s0 = c * 32;
        const int a = (lane >> 5) * 2;       // V-unit s-octet base for rep
        const int bq2 = lane & 31;           // V-unit hd quad
        bf16x8 kf[2][4];

        if (s0 + 32 <= sp) {
            // ================= all-cache chunk (f32 source) =================
            #pragma unroll
            for (int rep = 0; rep < 2; ++rep) {
                int ao = (rep * 64 + lane) >> 5;    // s octet 0..3
                int bq = (rep * 64 + lane) & 31;    // hd quad
                short tv[8][4];
                #pragma unroll
                for (int i = 0; i < 8; ++i) {
                    float4 v = *(const float4*)&vc[(((size_t)b * MAXS_ + s0 + ao * 8 + i) * H_ + h) * HD_ + bq * 4];
                    tv[i][0] = f2b(v.x); tv[i][1] = f2b(v.y); tv[i][2] = f2b(v.z); tv[i][3] = f2b(v.w);
                }
                #pragma unroll
                for (int j = 0; j < 4; ++j) {
                    int row = bq * 4 + j;
                    bf16x8 w;
                    #pragma unroll
                    for (int i = 0; i < 8; ++i) w[i] = tv[i][j];
                    int colB = (ao * 16) ^ (((row >> 4) & 3) << 4);
                    *(bf16x8*)((char*)&Vt[wave][row][0] + colB) = w;
                }
            }
            #pragma unroll
            for (int ct = 0; ct < 2; ++ct) {
                const float* kp = &kc[(((size_t)b * MAXS_ + s0 + ct * 16 + li) * H_ + h) * HD_];
                #pragma unroll
                for (int kk = 0; kk < 4; ++kk) {
                    float4 v0 = *(const float4*)(&kp[kk * 32 + lg * 8]);
                    float4 v1 = *(const float4*)(&kp[kk * 32 + lg * 8 + 4]);
                    bf16x8 f;
                    f[0] = f2b(v0.x); f[1] = f2b(v0.y); f[2] = f2b(v0.z); f[3] = f2b(v0.w);
                    f[4] = f2b(v1.x); f[5] = f2b(v1.y); f[6] = f2b(v1.z); f[7] = f2b(v1.w);
                    kf[ct][kk] = f;
                }
            }
        } else if (s0 >= sp) {
            // ================= all-fresh chunk (bf16 source) =================
            #pragma unroll
            for (int rep = 0; rep < 2; ++rep) {
                int ao = (rep * 64 + lane) >> 5;
                int bq = (rep * 64 + lane) & 31;
                short tv[8][4];
                #pragma unroll
                for (int i = 0; i < 8; ++i) {
                    int s = s0 + ao * 8 + i;
                    if (s < L) {
                        ushort4 u = *(const ushort4*)&vb[(((size_t)b * T_ + (s - sp)) * H_ + h) * HD_ + bq * 4];
                        tv[i][0] = (short)u.x; tv[i][1] = (short)u.y; tv[i][2] = (short)u.z; tv[i][3] = (short)u.w;
                    } else {
                        tv[i][0] = 0; tv[i][1] = 0; tv[i][2] = 0; tv[i][3] = 0;
                    }
                }
                #pragma unroll
                for (int j = 0; j < 4; ++j) {
                    int row = bq * 4 + j;
                    bf16x8 w;
                    #pragma unroll
                    for (int i = 0; i < 8; ++i) w[i] = tv[i][j];
                    int colB = (ao * 16) ^ (((row >> 4) & 3) << 4);
                    *(bf16x8*)((char*)&Vt[wave][row][0] + colB) = w;
                }
            }
            #pragma unroll
            for (int ct = 0; ct < 2; ++ct) {
                int s = s0 + ct * 16 + li;
                if (s < L) {
                    const bf16* kp = &kb[((size_t)(b * T_ + s - sp) * H_ + h) * HD_];
                    #pragma unroll
                    for (int kk = 0; kk < 4; ++kk)
                        kf[ct][kk] = *(const bf16x8*)(kp + kk * 32 + lg * 8);
                } else {
                    #pragma unroll
                    for (int kk = 0; kk < 4; ++kk) {
                        bf16x8 f;
                        #pragma unroll
                        for (int j = 0; j < 8; ++j) f[j] = 0;
                        kf[ct][kk] = f;
                    }
                }
            }
        } else {
            // ================= mixed chunk (general fallback) =================
            #pragma unroll
            for (int rep = 0; rep < 2; ++rep) {
                int ao = (rep * 64 + lane) >> 5;
                int bq = (rep * 64 + lane) & 31;
                short tv[8][4];
                #pragma unroll
                for (int i = 0; i < 8; ++i) {
                    int s = s0 + ao * 8 + i;
                    if (s < sp) {
                        float4 v = *(const float4*)&vc[(((size_t)b * MAXS_ + s) * H_ + h) * HD_ + bq * 4];
                        tv[i][0] = f2b(v.x); tv[i][1] = f2b(v.y); tv[i][2] = f2b(v.z); tv[i][3] = f2b(v.w);
                    } else if (s < L) {
                        ushort4 u = *(const ushort4*)&vb[(((size_t)b * T_ + (s - sp)) * H_ + h) * HD_ + bq * 4];
                        tv[i][0] = (short)u.x; tv[i][1] = (short)u.y; tv[i][2] = (short)u.z; tv[i][3] = (short)u.w;
                    } else {
                        tv[i][0] = 0; tv[i][1] = 0; tv[i][2] = 0; tv[i][3] = 0;
                    }
                }
                #pragma unroll
                for (int j = 0; j < 4; ++j) {
                    int row = bq * 4 + j;
                    bf16x8 w;
                    #pragma unroll
                    for (int i = 0; i < 8; ++i) w[i] = tv[i][j];
                    int colB = (ao * 16) ^ (((row >> 4) & 3) << 4);
                    *(bf16x8*)((char*)&Vt[wave][row][0] + colB) = w;
                }
            }
            #pragma unroll
            for (int ct = 0; ct < 2; ++ct) {
                int s = s0 + ct * 16 + li;
                if (s < sp) {
                    const float* kp = &kc[(((size_t)b * MAXS_ + s) * H_ + h) * HD_];
                    #pragma unroll
                    for (int kk = 0; kk < 4; ++kk) {
                        float4 v0 = *(const float4*)(&kp[kk * 32 + lg * 8]);
                        float4 v1 = *(const float4*)(&kp[kk * 32 + lg * 8 + 4]);
                        bf16x8 f;
                        f[0] = f2b(v0.x); f[1] = f2b(v0.y); f[2] = f2b(v0.z); f[3] = f2b(v0.w);
                        f[4] = f2b(v1.x); f[5] = f2b(v1.y); f[6] = f2b(v1.z); f[7] = f2b(v1.w);
                        kf[ct][kk] = f;
                    }
                } else if (s < L) {
                    const bf16* kp = &kb[((size_t)(b * T_ + s - sp) * H_ + h) * HD_];
                    #pragma unroll
                    for (int kk = 0; kk < 4; ++kk)
                        kf[ct][kk] = *(const bf16x8*)(kp + kk * 32 + lg * 8);
                } else {
                    #pragma unroll
                    for (int kk = 0; kk < 4; ++kk) {
                        bf16x8 f;
                        #pragma unroll
                        for (int j = 0; j < 8; ++j) f[j] = 0;
                        kf[ct][kk] = f;
                    }
                }
            }
        }
        (void)a; (void)bq2;

        // ---- swapped QK^T: sc[ct][rt] = K_slice x Q^T -> D[s16][q16] ----
        f32x4 sc[2][2];
        #pragma unroll
        for (int ct = 0; ct < 2; ++ct)
            #pragma unroll
            for (int rt = 0; rt < 2; ++rt) {
                f32x4 acc;
                for (int r = 0; r < 4; ++r) acc[r] = 0.f;
                #pragma unroll
                for (int kk = 0; kk < 4; ++kk)
                    acc = __builtin_amdgcn_mfma_f32_16x16x32_bf16(kf[ct][kk], qf[rt][kk], acc, 0, 0, 0);
                sc[ct][rt] = acc;
            }

        // ---- online softmax (lane li owns q-row; s-local = ct*16 + 4*lg + r) ----
        float corr[2];
        #pragma unroll
        for (int rt = 0; rt < 2; ++rt) {
            float xv[8];
            #pragma unroll
            for (int ct = 0; ct < 2; ++ct)
                #pragma unroll
                for (int r = 0; r < 4; ++r) {
                    float xx = sc[ct][rt][r] * scale;
                    if (s0 + ct * 16 + 4 * lg + r >= L) xx = -1e30f;
                    xv[ct * 4 + r] = xx;
                }
            float mx = fmaxf(fmaxf(fmaxf(xv[0], xv[1]), fmaxf(xv[2], xv[3])),
                             fmaxf(fmaxf(xv[4], xv[5]), fmaxf(xv[6], xv[7])));
            mx = fmaxf(mx, __shfl_xor(mx, 16, 64));
            mx = fmaxf(mx, __shfl_xor(mx, 32, 64));
            float mnew = fmaxf(m_r[rt], mx);
            corr[rt] = __expf(m_r[rt] - mnew);
            float p[8], ssum = 0.f;
            #pragma unroll
            for (int j = 0; j < 8; ++j) { p[j] = __expf(xv[j] - mnew); ssum += p[j]; }
            ssum += __shfl_xor(ssum, 16, 64);
            ssum += __shfl_xor(ssum, 32, 64);
            l_r[rt] = l_r[rt] * corr[rt] + ssum;
            m_r[rt] = mnew;
            #pragma unroll
            for (int ct = 0; ct < 2; ++ct)
                #pragma unroll
                for (int r = 0; r < 4; ++r)
                    Plds[wave][rt * 16 + li][ct * 16 + 4 * lg + r] = __float2bfloat16(p[ct * 4 + r]);
        }

        // redistribute corr from q=li indexing to q=4*lg+r indexing, rescale o
        #pragma unroll
        for (int rt = 0; rt < 2; ++rt) {
            float cq[4];
            #pragma unroll
            for (int r = 0; r < 4; ++r) cq[r] = __shfl(corr[rt], 20 * lg + r, 64);
            #pragma unroll
            for (int ht = 0; ht < 8; ++ht)
                #pragma unroll
                for (int r = 0; r < 4; ++r) o[rt][ht][r] *= cq[r];
        }

        // drain wave-private LDS writes (Vt + Plds) before cross-lane reads
        asm volatile("s_waitcnt lgkmcnt(0)" ::: "memory");
        bf16x8 pf[2];
        pf[0] = *(const bf16x8*)(&Plds[wave][li][lg * 8]);
        pf[1] = *(const bf16x8*)(&Plds[wave][16 + li][lg * 8]);

        // ---- PV from transposed LDS ----
        #pragma unroll
        for (int ht = 0; ht < 8; ++ht) {
            int row = ht * 16 + li;
            int colB = (lg * 16) ^ ((ht & 3) << 4);
            bf16x8 vf = *(const bf16x8*)((const char*)&Vt[wave][row][0] + colB);
            #pragma unroll
            for (int rt = 0; rt < 2; ++rt)
                o[rt][ht] = __builtin_amdgcn_mfma_f32_16x16x32_bf16(pf[rt], vf, o[rt][ht], 0, 0, 0);
        }
    }

    // ---- cross-wave combine ----
    if (lg == 0) {
        #pragma unroll
        for (int rt = 0; rt < 2; ++rt) {
            msh[wave][rt * 16 + li] = m_r[rt];
            lsh[wave][rt * 16 + li] = l_r[rt];
        }
    }
    __syncthreads();
    float corr2[2][4];
    #pragma unroll
    for (int rt = 0; rt < 2; ++rt)
        for (int r = 0; r < 4; ++r) {
            int row = rt * 16 + lg * 4 + r;
            float M = fmaxf(fmaxf(msh[0][row], msh[1][row]), fmaxf(msh[2][row], msh[3][row]));
            corr2[rt][r] = __expf(msh[wave][row] - M);
        }
    if (tid < 32) {
        int row = tid;
        float M = fmaxf(fmaxf(msh[0][row], msh[1][row]), fmaxf(msh[2][row], msh[3][row]));
        float lt = 0.f;
        #pragma unroll
        for (int w = 0; w < 4; ++w) lt += lsh[w][row] * __expf(msh[w][row] - M);
        ltot[row] = lt;
    }
    __syncthreads();
    for (int w = 0; w < 4; ++w) {
        if (wave == w) {
            #pragma unroll
            for (int rt = 0; rt < 2; ++rt)
                for (int ht = 0; ht < 8; ++ht)
                    for (int r = 0; r < 4; ++r) {
                        int row = rt * 16 + lg * 4 + r, col = ht * 16 + li;
                        float val = o[rt][ht][r] * corr2[rt][r];
                        if (w == 0) Osh[row][col] = val;
                        else Osh[row][col] += val;
                    }
        }
        __syncthreads();
    }
    {
        int row = tid >> 3;
        int c0 = (tid & 7) * 16;
        float inv = 1.0f / ltot[row];
        #pragma unroll
        for (int j = 0; j < 16; ++j)
            ob[(size_t)(b * T_ + row) * D_ + h * HD_ + c0 + j] = __float2bfloat16(Osh[row][c0 + j] * inv);
    }
}

extern "C" void kernel_launch(void* const* d_in, const int* in_sizes, int n_in,
                              void* d_out, int out_size, void* d_ws, size_t ws_size,
                              hipStream_t stream) {
    const float* x  = (const float*)d_in[0];
    const float* wq = (const float*)d_in[1];
    const float* wk = (const float*)d_in[2];
    const float* wv = (const float*)d_in[3];
    const float* wo = (const float*)d_in[4];
    const float* kc = (const float*)d_in[5];
    const float* vc = (const float*)d_in[6];
    const int*   sp = (const int*)d_in[7];

    char* ws = (char*)d_ws;
    const size_t MT = (size_t)M_ * D_;                 // 2M elements
    bf16* wt = (bf16*)ws;                              // 32 MiB (wo^T only)
    bf16* xb = wt + (size_t)D_ * D_;
    bf16* qb = xb + MT;
    bf16* kb = qb + MT;
    bf16* vb = kb + MT;
    bf16* ab = vb + MT;

    conv_x<<<dim3((int)(MT / 8 / 256)), 256, 0, stream>>>(x, xb);
    transpose_w<<<dim3(64, 64), 256, 0, stream>>>(wo, wt);
    gemm_qkvw<<<dim3(96, 8), 256, 0, stream>>>(xb, wq, wk, wv, qb);
    rope_inplace<<<dim3((int)(MT / 8 / 256)), 256, 0, stream>>>(qb, kb);
    attn<<<dim3(B_ * H_), 256, 0, stream>>>(qb, kb, vb, kc, vc, sp, ab);
    gemm_bf16t<64, 64><<<dim3(64, 8), 256, 0, stream>>>(ab, wt, (float*)d_out);
}